// Round 3
// baseline (31865.146 us; speedup 1.0000x reference)
//
#include <hip/hip_runtime.h>
#include <hip/hip_cooperative_groups.h>
#include <math.h>

namespace cg = cooperative_groups;

static constexpr int Bb   = 32;
static constexpr int Tt   = 500;
static constexpr int Ee   = 1024;
static constexpr int EMBc = 256;
static constexpr int Oo   = 5000;
static constexpr int Llen = 99;
static constexpr int OLEN = 100;
static constexpr int Aa   = 512;

// ---------------- precompute kernels ----------------

__global__ void k_ylens(const int* __restrict__ ys, int* __restrict__ ylens) {
    int b = threadIdx.x;
    if (b < Bb) {
        int c = 0;
        for (int i = 0; i < Llen; i++) c += (ys[b * Llen + i] != -1) ? 1 : 0;
        ylens[b] = c;
    }
}

__global__ void k_embed(const int* __restrict__ ys, const float* __restrict__ embed,
                        float* __restrict__ eys) {
    int blk = blockIdx.x;
    int b = blk / OLEN, i = blk % OLEN;
    int id = Oo - 1;  // sos
    if (i > 0) {
        int v = ys[b * Llen + i - 1];
        id = (v == -1) ? (Oo - 1) : v;
    }
    eys[(size_t)(b * OLEN + i) * EMBc + threadIdx.x] = embed[(size_t)id * EMBc + threadIdx.x];
}

__global__ void k_hmean(const float* __restrict__ hs, const int* __restrict__ hlens,
                        float* __restrict__ hm) {
    int b = blockIdx.y;
    int e = blockIdx.x * 256 + threadIdx.x;
    float sum = 0.f;
    for (int t = 0; t < Tt; t++) sum += hs[((size_t)b * Tt + t) * Ee + e];
    hm[(size_t)b * Ee + e] = sum / (float)hlens[b];
}

// C[M,N] = act(A[M,K] @ W[K,N] + bias). BM=128, BN=64, BK=16, 256 thr, micro 8x4.
template <int ACT>
__global__ void k_gemm_tiled(const float* __restrict__ Amat, const float* __restrict__ W,
                             const float* __restrict__ bias, float* __restrict__ C,
                             int M, int K, int N) {
    __shared__ float As[16][132];
    __shared__ float Wt[16][68];
    const int tid = threadIdx.x;
    const int row0 = blockIdx.y * 128;
    const int col0 = blockIdx.x * 64;
    const int ty = tid >> 4, tx = tid & 15;
    float acc[8][4] = {};
    for (int kk = 0; kk < K; kk += 16) {
#pragma unroll
        for (int rr = 0; rr < 128; rr += 64) {
            int r = rr + (tid >> 2);
            int c4 = (tid & 3) * 4;
            float4 v = make_float4(0.f, 0.f, 0.f, 0.f);
            if (row0 + r < M) v = *(const float4*)(&Amat[(size_t)(row0 + r) * K + kk + c4]);
            As[c4 + 0][r] = v.x; As[c4 + 1][r] = v.y; As[c4 + 2][r] = v.z; As[c4 + 3][r] = v.w;
        }
        for (int i = tid; i < 16 * 64; i += 256)
            Wt[i >> 6][i & 63] = W[(size_t)(kk + (i >> 6)) * N + col0 + (i & 63)];
        __syncthreads();
#pragma unroll
        for (int k = 0; k < 16; k++) {
            float a[8], bbv[4];
#pragma unroll
            for (int i = 0; i < 8; i++) a[i] = As[k][ty * 8 + i];
#pragma unroll
            for (int j = 0; j < 4; j++) bbv[j] = Wt[k][tx * 4 + j];
#pragma unroll
            for (int i = 0; i < 8; i++)
#pragma unroll
                for (int j = 0; j < 4; j++) acc[i][j] += a[i] * bbv[j];
        }
        __syncthreads();
    }
#pragma unroll
    for (int i = 0; i < 8; i++) {
        int r = row0 + ty * 8 + i;
        if (r < M) {
#pragma unroll
            for (int j = 0; j < 4; j++) {
                int cc = col0 + tx * 4 + j;
                float v = acc[i][j];
                if (bias) v += bias[cc];
                if (ACT == 1) v = tanhf(v);
                C[(size_t)r * N + cc] = v;
            }
        }
    }
}

// ---------------- persistent recurrence kernel (cooperative) ----------------
// Phase bodies are verbatim ports of the round-2 per-step kernels; identical
// arithmetic & summation order. smem is a manually-unioned 18KB buffer
// (max phase need: cell2 x-stage 32*128 floats = 16KB) so LDS never caps
// the 1-block/CU co-residency that grid.sync() requires.

// 3-acc split-K GEMM chunk: x[32,K] vs Wg (2048-wide: cols j, j+1024), Wx (1024-wide).
template <int KC>
__device__ __forceinline__ void gemm3_body(const float* __restrict__ x, int ldx,
                                           const float* __restrict__ Wga, const float* __restrict__ Wgb,
                                           const float* __restrict__ Wxa, const float* __restrict__ Wxb,
                                           int kSeg, float* __restrict__ P, int jb, int kc,
                                           float* __restrict__ xs) {
    const int tid = threadIdx.x;
    const int k0 = kc * KC;
    for (int i = tid; i < Bb * KC; i += 256) {
        int bb = i / KC, k = i - bb * KC;
        xs[bb * KC + k] = x[(size_t)bb * ldx + k0 + k];
    }
    __syncthreads();
    const int tx = tid & 63, ty = tid >> 6;
    const int j = jb * 64 + tx;
    const int b0 = ty * 8;
    const bool seg0 = (k0 < kSeg);
    const float* Wg = seg0 ? Wga : Wgb;
    const float* Wx = seg0 ? Wxa : Wxb;
    const int kbase = seg0 ? k0 : (k0 - kSeg);
    float ag[8] = {}, au[8] = {}, ax[8] = {};
    for (int kk = 0; kk < KC; kk++) {
        const float* wgr = Wg + (size_t)(kbase + kk) * 2048;
        const float* wxr = Wx + (size_t)(kbase + kk) * 1024;
        float wg0 = wgr[j], wg1 = wgr[j + 1024], wx0 = wxr[j];
#pragma unroll
        for (int i = 0; i < 8; i++) {
            float xv = xs[(b0 + i) * KC + kk];
            ag[i] += xv * wg0;
            au[i] += xv * wg1;
            ax[i] += xv * wx0;
        }
    }
#pragma unroll
    for (int i = 0; i < 8; i++) {
        P[(((size_t)kc * 3 + 0) * Bb + b0 + i) * 1024 + j] = ag[i];
        P[(((size_t)kc * 3 + 1) * Bb + b0 + i) * 1024 + j] = au[i];
        P[(((size_t)kc * 3 + 2) * Bb + b0 + i) * 1024 + j] = ax[i];
    }
    __syncthreads();  // smem reuse guard
}

// 1-acc split-K GEMM chunk (dq): partials P[(kc*32 + b)*N + j]
template <int KC>
__device__ __forceinline__ void gemm1_body(const float* __restrict__ x, int ldx,
                                           const float* __restrict__ W, int N,
                                           float* __restrict__ P, int jb, int kc,
                                           float* __restrict__ xs) {
    const int tid = threadIdx.x;
    const int k0 = kc * KC;
    for (int i = tid; i < Bb * KC; i += 256) {
        int bb = i / KC, k = i - bb * KC;
        xs[bb * KC + k] = x[(size_t)bb * ldx + k0 + k];
    }
    __syncthreads();
    const int tx = tid & 63, ty = tid >> 6;
    const int j = jb * 64 + tx;
    const int b0 = ty * 8;
    float acc[8] = {};
    for (int kk = 0; kk < KC; kk++) {
        float w = W[(size_t)(k0 + kk) * N + j];
#pragma unroll
        for (int i = 0; i < 8; i++) acc[i] += xs[(b0 + i) * KC + kk] * w;
    }
#pragma unroll
    for (int i = 0; i < 8; i++) P[((size_t)kc * Bb + b0 + i) * N + j] = acc[i];
    __syncthreads();
}

__global__ __launch_bounds__(256, 1) void k_recur(
    const float* __restrict__ hs, const int* __restrict__ hlens, const int* __restrict__ ylens,
    const float* __restrict__ U1, const float* __restrict__ Ux1,
    const float* __restrict__ U2, const float* __restrict__ b2, const float* __restrict__ Wc,
    const float* __restrict__ Ux2, const float* __restrict__ bUx2, const float* __restrict__ Wcx,
    const float* __restrict__ Wdec, const float* __restrict__ sb, const float* __restrict__ sbx,
    const float* __restrict__ enc_att,
    float* __restrict__ h, float* __restrict__ xall, float* __restrict__ en,
    float* __restrict__ pd, float* __restrict__ p3) {
    cg::grid_group grid = cg::this_grid();
    __shared__ float smem[4608];  // 18KB union buffer
    const int tid = threadIdx.x;
    const int nb = gridDim.x;

    for (int s = 0; s < OLEN; s++) {
        float* x23s = xall + (size_t)s * Bb * 2048;

        // P1: cell1 split-K partials (256 tasks) + zero c-half of x23s (128 tasks)
        for (int task = blockIdx.x; task < 384; task += nb) {
            if (task < 256) {
                gemm3_body<64>(h, 1024, U1, U1, Ux1, Ux1, 1024, p3, task & 15, task >> 4, smem);
            } else {
                int idx = (task - 256) * 256 + tid;
                x23s[((idx >> 10) * 2048) + 1024 + (idx & 1023)] = 0.f;
            }
        }
        grid.sync();

        // P2: comb1 -> h1 into x23s left half (128 tasks x 256 elems)
        for (int task = blockIdx.x; task < 128; task += nb) {
            int gid = task * 256 + tid;
            int b = gid >> 10, j = gid & 1023;
            float s0 = 0, s1 = 0, sx = 0;
#pragma unroll
            for (int kc = 0; kc < 16; kc++) {
                s0 += p3[(((size_t)kc * 3 + 0) * Bb + b) * 1024 + j];
                s1 += p3[(((size_t)kc * 3 + 1) * Bb + b) * 1024 + j];
                sx += p3[(((size_t)kc * 3 + 2) * Bb + b) * 1024 + j];
            }
            float r = 1.f / (1.f + expf(-(s0 + sb[((size_t)b * OLEN + s) * 2048 + j])));
            float u = 1.f / (1.f + expf(-(s1 + sb[((size_t)b * OLEN + s) * 2048 + 1024 + j])));
            float ht = tanhf(sx * r + sbx[((size_t)b * OLEN + s) * 1024 + j]);
            float hp = h[(size_t)b * 1024 + j];
            float h1 = u * hp + (1.f - u) * ht;
            float m = (s < ylens[b] + 1) ? 1.f : 0.f;
            h1 = m * h1 + (1.f - m) * hp;
            x23s[(size_t)b * 2048 + j] = h1;
        }
        grid.sync();

        // P3: dq split-K partials (8 jout x 16 kc = 128 tasks)
        for (int task = blockIdx.x; task < 128; task += nb)
            gemm1_body<64>(x23s, 2048, Wdec, 512, pd, task & 7, task >> 3, smem);
        grid.sync();

        // P4: attention scores en[b,t] (256 tasks: b*8 + tt)
        for (int task = blockIdx.x; task < 256; task += nb) {
            int b = task >> 3, tt = task & 7;
            float* dqs = smem;
            for (int jj = tid; jj < Aa; jj += 256) {
                float sum = 0;
#pragma unroll
                for (int kc = 0; kc < 16; kc++) sum += pd[((size_t)kc * Bb + b) * Aa + jj];
                dqs[jj] = tanhf(sum);
            }
            __syncthreads();
            const int tx = tid & 63, ty = tid >> 6;
            for (int t2 = 0; t2 < 64; t2 += 4) {
                int t = tt * 64 + t2 + ty;
                if (t < Tt) {  // wave-uniform
                    float acc = 0;
                    const float* er = enc_att + ((size_t)b * Tt + t) * Aa;
#pragma unroll
                    for (int i = 0; i < 8; i++) acc += er[tx + 64 * i] * dqs[tx + 64 * i];
#pragma unroll
                    for (int off = 32; off > 0; off >>= 1) acc += __shfl_down(acc, off, 64);
                    if (tx == 0) en[(size_t)b * 512 + t] = acc;
                }
            }
            __syncthreads();
        }
        grid.sync();

        // P5: softmax + context (128 tasks: b*4 + tc), 256 thr covers all 1024 e
        for (int task = blockIdx.x; task < 128; task += nb) {
            int b = task >> 2, tc = task & 3;
            float* wts = smem;        // 512
            float* red = smem + 512;  // 256
            const int hlen = hlens[b];
            float mx = -1e30f;
            for (int t = tid; t < hlen; t += 256) mx = fmaxf(mx, en[(size_t)b * 512 + t]);
            red[tid] = mx;
            __syncthreads();
            for (int w = 128; w > 0; w >>= 1) {
                if (tid < w) red[tid] = fmaxf(red[tid], red[tid + w]);
                __syncthreads();
            }
            mx = red[0];
            __syncthreads();
            float ps = 0;
            for (int t = tid; t < Tt; t += 256) {
                float w = 0.f;
                if (t < hlen) w = expf(en[(size_t)b * 512 + t] - mx);
                wts[t] = w;
                ps += w;
            }
            red[tid] = ps;
            __syncthreads();
            for (int w = 128; w > 0; w >>= 1) {
                if (tid < w) red[tid] += red[tid + w];
                __syncthreads();
            }
            float inv = 1.f / red[0];
            __syncthreads();
            for (int t = tid; t < Tt; t += 256) wts[t] *= inv;
            __syncthreads();

            const int e0 = tid * 4;
            int tstart = tc * 125;
            int tend = tstart + 125;
            if (tend > hlen) tend = hlen;
            float4 a0 = make_float4(0, 0, 0, 0), a1 = make_float4(0, 0, 0, 0);
            float4 a2 = make_float4(0, 0, 0, 0), a3 = make_float4(0, 0, 0, 0);
            int t = tstart;
            for (; t + 3 < tend; t += 4) {
                float w0 = wts[t], w1 = wts[t + 1], w2 = wts[t + 2], w3 = wts[t + 3];
                float4 h0 = *(const float4*)(&hs[((size_t)b * Tt + t) * Ee + e0]);
                float4 h1 = *(const float4*)(&hs[((size_t)b * Tt + t + 1) * Ee + e0]);
                float4 h2 = *(const float4*)(&hs[((size_t)b * Tt + t + 2) * Ee + e0]);
                float4 h3 = *(const float4*)(&hs[((size_t)b * Tt + t + 3) * Ee + e0]);
                a0.x += w0 * h0.x; a0.y += w0 * h0.y; a0.z += w0 * h0.z; a0.w += w0 * h0.w;
                a1.x += w1 * h1.x; a1.y += w1 * h1.y; a1.z += w1 * h1.z; a1.w += w1 * h1.w;
                a2.x += w2 * h2.x; a2.y += w2 * h2.y; a2.z += w2 * h2.z; a2.w += w2 * h2.w;
                a3.x += w3 * h3.x; a3.y += w3 * h3.y; a3.z += w3 * h3.z; a3.w += w3 * h3.w;
            }
            for (; t < tend; t++) {
                float w = wts[t];
                float4 hv = *(const float4*)(&hs[((size_t)b * Tt + t) * Ee + e0]);
                a0.x += w * hv.x; a0.y += w * hv.y; a0.z += w * hv.z; a0.w += w * hv.w;
            }
            a0.x += a1.x + a2.x + a3.x;
            a0.y += a1.y + a2.y + a3.y;
            a0.z += a1.z + a2.z + a3.z;
            a0.w += a1.w + a2.w + a3.w;
            float* cdst = &x23s[(size_t)b * 2048 + 1024 + e0];
            atomicAdd(cdst + 0, a0.x);
            atomicAdd(cdst + 1, a0.y);
            atomicAdd(cdst + 2, a0.z);
            atomicAdd(cdst + 3, a0.w);
            __syncthreads();
        }
        grid.sync();

        // P6: cell2 split-K partials over [h1|c], K=2048 (256 tasks)
        for (int task = blockIdx.x; task < 256; task += nb)
            gemm3_body<128>(x23s, 2048, U2, Wc, Ux2, Wcx, 1024, p3, task & 15, task >> 4, smem);
        grid.sync();

        // P7: comb2 -> h2 (in-place x23s left half + next-step h) (128 tasks)
        for (int task = blockIdx.x; task < 128; task += nb) {
            int gid = task * 256 + tid;
            int b = gid >> 10, j = gid & 1023;
            float s0 = 0, s1 = 0, xa = 0, xb = 0;
#pragma unroll
            for (int kc = 0; kc < 16; kc++) {
                s0 += p3[(((size_t)kc * 3 + 0) * Bb + b) * 1024 + j];
                s1 += p3[(((size_t)kc * 3 + 1) * Bb + b) * 1024 + j];
                float px = p3[(((size_t)kc * 3 + 2) * Bb + b) * 1024 + j];
                if (kc < 8) xa += px; else xb += px;
            }
            float r = 1.f / (1.f + expf(-(s0 + b2[j])));
            float u = 1.f / (1.f + expf(-(s1 + b2[1024 + j])));
            float h2t = tanhf((xa + bUx2[j]) * r + xb);
            float h1v = x23s[(size_t)b * 2048 + j];
            float h2 = u * h1v + (1.f - u) * h2t;
            float m = (s < ylens[b] + 1) ? 1.f : 0.f;
            h2 = m * h2 + (1.f - m) * h1v;
            x23s[(size_t)b * 2048 + j] = h2;
            h[(size_t)b * 1024 + j] = h2;
        }
        grid.sync();
    }
}

// ---------------- batched final phase ----------------

__global__ void k_gemmL(const float* __restrict__ x23a, const float* __restrict__ eys,
                        const float* __restrict__ Ws, const float* __restrict__ We,
                        const float* __restrict__ Wy, const float* __restrict__ bs,
                        float* __restrict__ mo) {
    __shared__ float As[16][132];
    __shared__ float Wt[16][68];
    const int tid = threadIdx.x;
    const int row0 = blockIdx.y * 128;
    const int col0 = blockIdx.x * 64;
    const int ty = tid >> 4, tx = tid & 15;
    float acc[8][4] = {};
    for (int kk = 0; kk < 2304; kk += 16) {
#pragma unroll
        for (int rr = 0; rr < 128; rr += 64) {
            int rl = rr + (tid >> 2);
            int r = row0 + rl;
            int c4 = (tid & 3) * 4;
            float4 v;
            if (kk < 2048) {
                v = *(const float4*)(&x23a[(size_t)r * 2048 + kk + c4]);
            } else {
                int bI = r & 31, sI = r >> 5;
                v = *(const float4*)(&eys[((size_t)bI * OLEN + sI) * EMBc + (kk - 2048) + c4]);
            }
            As[c4 + 0][rl] = v.x; As[c4 + 1][rl] = v.y; As[c4 + 2][rl] = v.z; As[c4 + 3][rl] = v.w;
        }
        for (int i = tid; i < 16 * 64; i += 256) {
            int rowk = kk + (i >> 6);
            const float* wr = (rowk < 1024) ? &Ws[(size_t)rowk * 1024]
                             : (rowk < 2048) ? &We[(size_t)(rowk - 1024) * 1024]
                                             : &Wy[(size_t)(rowk - 2048) * 1024];
            Wt[i >> 6][i & 63] = wr[col0 + (i & 63)];
        }
        __syncthreads();
#pragma unroll
        for (int k = 0; k < 16; k++) {
            float a[8], bbv[4];
#pragma unroll
            for (int i = 0; i < 8; i++) a[i] = As[k][ty * 8 + i];
#pragma unroll
            for (int j = 0; j < 4; j++) bbv[j] = Wt[k][tx * 4 + j];
#pragma unroll
            for (int i = 0; i < 8; i++)
#pragma unroll
                for (int j = 0; j < 4; j++) acc[i][j] += a[i] * bbv[j];
        }
        __syncthreads();
    }
#pragma unroll
    for (int i = 0; i < 8; i++) {
        int r = row0 + ty * 8 + i;
#pragma unroll
        for (int p = 0; p < 2; p++) {
            int c = col0 + tx * 4 + p * 2;
            float v0 = acc[i][p * 2 + 0] + bs[c + 0];
            float v1 = acc[i][p * 2 + 1] + bs[c + 1];
            mo[(size_t)r * 512 + (c >> 1)] = fmaxf(v0, v1);
        }
    }
}

__global__ void k_gemmZ(const float* __restrict__ mo, const float* __restrict__ Wl,
                        const float* __restrict__ bl, float* __restrict__ out) {
    __shared__ float As[16][132];
    __shared__ float Wt[16][68];
    const int tid = threadIdx.x;
    const int row0 = blockIdx.y * 128;
    const int col0 = blockIdx.x * 64;
    const int ty = tid >> 4, tx = tid & 15;
    float acc[8][4] = {};
    for (int kk = 0; kk < 512; kk += 16) {
#pragma unroll
        for (int rr = 0; rr < 128; rr += 64) {
            int rl = rr + (tid >> 2);
            int r = row0 + rl;
            int c4 = (tid & 3) * 4;
            float4 v = *(const float4*)(&mo[(size_t)r * 512 + kk + c4]);
            As[c4 + 0][rl] = v.x; As[c4 + 1][rl] = v.y; As[c4 + 2][rl] = v.z; As[c4 + 3][rl] = v.w;
        }
        for (int i = tid; i < 16 * 64; i += 256) {
            int c = col0 + (i & 63);
            if (c > Oo - 1) c = Oo - 1;
            Wt[i >> 6][i & 63] = Wl[(size_t)(kk + (i >> 6)) * Oo + c];
        }
        __syncthreads();
#pragma unroll
        for (int k = 0; k < 16; k++) {
            float a[8], bbv[4];
#pragma unroll
            for (int i = 0; i < 8; i++) a[i] = As[k][ty * 8 + i];
#pragma unroll
            for (int j = 0; j < 4; j++) bbv[j] = Wt[k][tx * 4 + j];
#pragma unroll
            for (int i = 0; i < 8; i++)
#pragma unroll
                for (int j = 0; j < 4; j++) acc[i][j] += a[i] * bbv[j];
        }
        __syncthreads();
    }
#pragma unroll
    for (int i = 0; i < 8; i++) {
        int r = row0 + ty * 8 + i;
        int bI = r & 31, sI = r >> 5;
        float* zr = out + ((size_t)bI * OLEN + sI) * Oo;
#pragma unroll
        for (int j = 0; j < 4; j++) {
            int c = col0 + tx * 4 + j;
            if (c < Oo) zr[c] = acc[i][j] + bl[c];
        }
    }
}

__global__ void k_osm(float* __restrict__ out) {
    __shared__ float red[256];
    __shared__ float ev[Oo];
    const int tid = threadIdx.x;
    const int r = blockIdx.x;
    const int bI = r & 31, sI = r >> 5;
    float* zr = out + ((size_t)bI * OLEN + sI) * Oo;
    float mx = -1e30f;
    for (int i = tid; i < Oo; i += 256) mx = fmaxf(mx, zr[i]);
    red[tid] = mx;
    __syncthreads();
    for (int w = 128; w > 0; w >>= 1) {
        if (tid < w) red[tid] = fmaxf(red[tid], red[tid + w]);
        __syncthreads();
    }
    mx = red[0];
    __syncthreads();
    float ps = 0;
    for (int i = tid; i < Oo; i += 256) {
        float e = expf(zr[i] - mx);
        ev[i] = e;
        ps += e;
    }
    red[tid] = ps;
    __syncthreads();
    for (int w = 128; w > 0; w >>= 1) {
        if (tid < w) red[tid] += red[tid + w];
        __syncthreads();
    }
    float inv = 1.f / red[0];
    for (int i = tid; i < Oo; i += 256) zr[i] = ev[i] * inv;
}

// ---------------- launch ----------------

extern "C" void kernel_launch(void* const* d_in, const int* in_sizes, int n_in,
                              void* d_out, int out_size, void* d_ws, size_t ws_size,
                              hipStream_t stream) {
    const float* hs    = (const float*)d_in[0];
    const int*   hlens = (const int*)d_in[1];
    const int*   ys    = (const int*)d_in[2];
    const float* embed = (const float*)d_in[3];
    const float* W1_W  = (const float*)d_in[4];
    const float* b1_W  = (const float*)d_in[5];
    const float* W1_Wx = (const float*)d_in[6];
    const float* b1_Wx = (const float*)d_in[7];
    const float* U1    = (const float*)d_in[8];
    const float* Ux1   = (const float*)d_in[9];
    const float* U2    = (const float*)d_in[10];
    const float* b2    = (const float*)d_in[11];
    const float* Wc    = (const float*)d_in[12];
    const float* Ux2   = (const float*)d_in[13];
    const float* bUx2  = (const float*)d_in[14];
    const float* Wcx   = (const float*)d_in[15];
    const float* Winit = (const float*)d_in[16];
    const float* binit = (const float*)d_in[17];
    const float* Ws    = (const float*)d_in[18];
    const float* bs    = (const float*)d_in[19];
    const float* Wy    = (const float*)d_in[20];
    const float* We    = (const float*)d_in[21];
    const float* Wlog  = (const float*)d_in[22];
    const float* blog  = (const float*)d_in[23];
    const float* Wenc  = (const float*)d_in[24];
    const float* Wdec  = (const float*)d_in[25];
    float* out = (float*)d_out;
    float* wsp = (float*)d_ws;

    // ws layout (floats) -- total ~20.7M floats = ~83 MB
    float* enc_att = wsp;                                    // 32*500*512   = 8,192,000
    float* sb      = enc_att + (size_t)Bb * Tt * Aa;         // 32*100*2048  = 6,553,600
    float* sbx     = sb      + (size_t)Bb * OLEN * 2048;     // 32*100*1024  = 3,276,800
    float* eys     = sbx     + (size_t)Bb * OLEN * 1024;     // 32*100*256   =   819,200
    float* h       = eys     + (size_t)Bb * OLEN * EMBc;     // 32*1024
    float* en      = h       + (size_t)Bb * 1024;            // 32*512
    float* pd      = en      + (size_t)Bb * 512;             // 16*32*512    =   262,144
    float* p3      = pd      + (size_t)16 * Bb * 512;        // 16*3*32*1024 = 1,572,864
    int*   ylens   = (int*)(p3 + (size_t)16 * 3 * Bb * 1024);
    float* hm      = pd;   // alias: precompute only, before pd's first write
    float* mo      = pd;   // alias: final phase only (1,638,400 <= 1,835,008)
    // [h2|c] per step hosted in d_out (dead until final phase): 3200 x 2048 row-major
    float* xall    = out;

    // ---- precompute ----
    k_ylens<<<1, 64, 0, stream>>>(ys, ylens);
    k_embed<<<Bb * OLEN, EMBc, 0, stream>>>(ys, embed, eys);
    k_hmean<<<dim3(4, Bb), 256, 0, stream>>>(hs, hlens, hm);
    k_gemm_tiled<0><<<dim3(16, 1), 256, 0, stream>>>(hm, Winit, binit, h, Bb, 1024, 1024);
    k_gemm_tiled<0><<<dim3(32, 25), 256, 0, stream>>>(eys, W1_W, b1_W, sb, Bb * OLEN, EMBc, 2048);
    k_gemm_tiled<0><<<dim3(16, 25), 256, 0, stream>>>(eys, W1_Wx, b1_Wx, sbx, Bb * OLEN, EMBc, 1024);
    k_gemm_tiled<1><<<dim3(8, 125), 256, 0, stream>>>(hs, Wenc, nullptr, enc_att, Bb * Tt, Ee, Aa);

    // ---- recurrence: one persistent cooperative kernel, grid.sync between phases ----
    {
        void* cargs[] = {
            (void*)&hs, (void*)&hlens, (void*)&ylens,
            (void*)&U1, (void*)&Ux1,
            (void*)&U2, (void*)&b2, (void*)&Wc,
            (void*)&Ux2, (void*)&bUx2, (void*)&Wcx,
            (void*)&Wdec, (void*)&sb, (void*)&sbx, (void*)&enc_att,
            (void*)&h, (void*)&xall, (void*)&en, (void*)&pd, (void*)&p3
        };
        hipLaunchCooperativeKernel((const void*)k_recur, dim3(256), dim3(256), cargs, 0, stream);
    }

    // ---- batched logit path over all (b, s) ----
    k_gemmL<<<dim3(16, 25), 256, 0, stream>>>(xall, eys, Ws, We, Wy, bs, mo);
    k_gemmZ<<<dim3(79, 25), 256, 0, stream>>>(mo, Wlog, blog, out);
    k_osm<<<Bb * OLEN, 256, 0, stream>>>(out);
}

// Round 4
// 12109.602 us; speedup vs baseline: 2.6314x; 2.6314x over previous
//
#include <hip/hip_runtime.h>
#include <math.h>

static constexpr int Bb   = 32;
static constexpr int Tt   = 500;
static constexpr int Ee   = 1024;
static constexpr int EMBc = 256;
static constexpr int Oo   = 5000;
static constexpr int Llen = 99;
static constexpr int OLEN = 100;
static constexpr int Aa   = 512;

// ---------------- precompute kernels ----------------

__global__ void k_ylens(const int* __restrict__ ys, int* __restrict__ ylens) {
    int b = threadIdx.x;
    if (b < Bb) {
        int c = 0;
        for (int i = 0; i < Llen; i++) c += (ys[b * Llen + i] != -1) ? 1 : 0;
        ylens[b] = c;
    }
}

__global__ void k_embed(const int* __restrict__ ys, const float* __restrict__ embed,
                        float* __restrict__ eys) {
    int blk = blockIdx.x;
    int b = blk / OLEN, i = blk % OLEN;
    int id = Oo - 1;  // sos
    if (i > 0) {
        int v = ys[b * Llen + i - 1];
        id = (v == -1) ? (Oo - 1) : v;
    }
    eys[(size_t)(b * OLEN + i) * EMBc + threadIdx.x] = embed[(size_t)id * EMBc + threadIdx.x];
}

__global__ void k_hmean(const float* __restrict__ hs, const int* __restrict__ hlens,
                        float* __restrict__ hm) {
    int b = blockIdx.y;
    int e = blockIdx.x * 256 + threadIdx.x;
    float sum = 0.f;
    for (int t = 0; t < Tt; t++) sum += hs[((size_t)b * Tt + t) * Ee + e];
    hm[(size_t)b * Ee + e] = sum / (float)hlens[b];
}

// C[M,N] = act(A[M,K] @ W[K,N] + bias). BM=BN=128, BK=16, 256 thr, micro 8x8.
// N multiple of 128, K multiple of 16; M guarded.
template <int ACT>
__global__ __launch_bounds__(256) void k_gemm128(const float* __restrict__ A,
                                                 const float* __restrict__ W,
                                                 const float* __restrict__ bias,
                                                 float* __restrict__ C,
                                                 int M, int K, int N) {
    __shared__ float As[16][132];
    __shared__ float Bs[16][132];
    const int tid = threadIdx.x;
    const int row0 = blockIdx.y * 128, col0 = blockIdx.x * 128;
    const int ty = tid >> 4, tx = tid & 15;
    float acc[8][8] = {};
    for (int kk = 0; kk < K; kk += 16) {
#pragma unroll
        for (int l = 0; l < 2; l++) {
            int idx = tid + l * 256;
            int r = idx >> 2, c4 = (idx & 3) * 4;
            float4 v = make_float4(0.f, 0.f, 0.f, 0.f);
            if (row0 + r < M) v = *(const float4*)(&A[(size_t)(row0 + r) * K + kk + c4]);
            As[c4 + 0][r] = v.x; As[c4 + 1][r] = v.y; As[c4 + 2][r] = v.z; As[c4 + 3][r] = v.w;
        }
#pragma unroll
        for (int l = 0; l < 2; l++) {
            int idx = tid + l * 256;
            int r = idx >> 5, c4 = (idx & 31) * 4;
            float4 v = *(const float4*)(&W[(size_t)(kk + r) * N + col0 + c4]);
            Bs[r][c4 + 0] = v.x; Bs[r][c4 + 1] = v.y; Bs[r][c4 + 2] = v.z; Bs[r][c4 + 3] = v.w;
        }
        __syncthreads();
#pragma unroll
        for (int k = 0; k < 16; k++) {
            float a[8], b[8];
#pragma unroll
            for (int i = 0; i < 8; i++) a[i] = As[k][ty * 8 + i];
#pragma unroll
            for (int j = 0; j < 8; j++) b[j] = Bs[k][tx * 8 + j];
#pragma unroll
            for (int i = 0; i < 8; i++)
#pragma unroll
                for (int j = 0; j < 8; j++) acc[i][j] += a[i] * b[j];
        }
        __syncthreads();
    }
#pragma unroll
    for (int i = 0; i < 8; i++) {
        int r = row0 + ty * 8 + i;
        if (r < M) {
#pragma unroll
            for (int j = 0; j < 8; j++) {
                int c = col0 + tx * 8 + j;
                float v = acc[i][j];
                if (bias) v += bias[c];
                if (ACT == 1) v = tanhf(v);
                C[(size_t)r * N + c] = v;
            }
        }
    }
}

// ---------------- per-step kernels (5 launches/step) ----------------

// K1: cell1 split-K GEMM; staging = h2 of prev step, recomputed in-block from
// p3b partials (fused comb2). jb==0 blocks publish h2 to `h` and x23 of step s-1.
// s==0: read h0 directly (useDirect=1).
__global__ __launch_bounds__(256) void k_cell1(
    const float* __restrict__ hDirect, int useDirect,
    const float* __restrict__ p3b, const float* __restrict__ h1buf,
    const float* __restrict__ b2, const float* __restrict__ bUx2,
    const int* __restrict__ ylens, int sPrev,
    const float* __restrict__ U1, const float* __restrict__ Ux1,
    float* __restrict__ p3a, float* __restrict__ hOut, float* __restrict__ x23prev) {
    __shared__ float xs[Bb * 64];
    const int tid = threadIdx.x;
    const int jb = blockIdx.x, kc = blockIdx.y;
    const int k0 = kc * 64;
    if (useDirect) {
        for (int i = tid; i < Bb * 64; i += 256) {
            int bb = i >> 6, kk = i & 63;
            xs[i] = hDirect[(size_t)bb * 1024 + k0 + kk];
        }
    } else {
        for (int i = tid; i < Bb * 64; i += 256) {
            int bb = i >> 6, kk = i & 63;
            int j = k0 + kk;
            float s0 = 0, s1 = 0, xa = 0, xb = 0;
#pragma unroll
            for (int kc2 = 0; kc2 < 16; kc2++) {
                s0 += p3b[(((size_t)kc2 * 3 + 0) * Bb + bb) * 1024 + j];
                s1 += p3b[(((size_t)kc2 * 3 + 1) * Bb + bb) * 1024 + j];
                float px = p3b[(((size_t)kc2 * 3 + 2) * Bb + bb) * 1024 + j];
                if (kc2 < 8) xa += px; else xb += px;
            }
            float r = 1.f / (1.f + expf(-(s0 + b2[j])));
            float u = 1.f / (1.f + expf(-(s1 + b2[1024 + j])));
            float h2t = tanhf((xa + bUx2[j]) * r + xb);
            float h1v = h1buf[(size_t)bb * 1024 + j];
            float h2 = u * h1v + (1.f - u) * h2t;
            float m = (sPrev < ylens[bb] + 1) ? 1.f : 0.f;
            h2 = m * h2 + (1.f - m) * h1v;
            xs[i] = h2;
            if (jb == 0) {
                hOut[(size_t)bb * 1024 + j] = h2;
                x23prev[(size_t)bb * 2048 + j] = h2;
            }
        }
    }
    __syncthreads();
    const int tx = tid & 63, ty = tid >> 6;
    const int j = jb * 64 + tx;
    const int b0 = ty * 8;
    float ag[8] = {}, au[8] = {}, ax[8] = {};
    for (int kk = 0; kk < 64; kk++) {
        const float* wgr = U1 + (size_t)(k0 + kk) * 2048;
        const float* wxr = Ux1 + (size_t)(k0 + kk) * 1024;
        float wg0 = wgr[j], wg1 = wgr[j + 1024], wx0 = wxr[j];
#pragma unroll
        for (int i = 0; i < 8; i++) {
            float xv = xs[(b0 + i) * 64 + kk];
            ag[i] += xv * wg0;
            au[i] += xv * wg1;
            ax[i] += xv * wx0;
        }
    }
#pragma unroll
    for (int i = 0; i < 8; i++) {
        p3a[(((size_t)kc * 3 + 0) * Bb + b0 + i) * 1024 + j] = ag[i];
        p3a[(((size_t)kc * 3 + 1) * Bb + b0 + i) * 1024 + j] = au[i];
        p3a[(((size_t)kc * 3 + 2) * Bb + b0 + i) * 1024 + j] = ax[i];
    }
}

// K2: dq split-K GEMM; staging = h1, recomputed in-block from p3a (fused comb1).
// jb==0 blocks publish h1 to h1buf.
__global__ __launch_bounds__(256) void k_dq(
    const float* __restrict__ p3a, const float* __restrict__ sb,
    const float* __restrict__ sbx, const float* __restrict__ h,
    const int* __restrict__ ylens, int s,
    const float* __restrict__ Wdec, float* __restrict__ pd, float* __restrict__ h1buf) {
    __shared__ float xs[Bb * 64];
    const int tid = threadIdx.x;
    const int jb = blockIdx.x, kc = blockIdx.y;
    const int k0 = kc * 64;
    for (int i = tid; i < Bb * 64; i += 256) {
        int bb = i >> 6, kk = i & 63;
        int j = k0 + kk;
        float s0 = 0, s1 = 0, sx = 0;
#pragma unroll
        for (int kc2 = 0; kc2 < 16; kc2++) {
            s0 += p3a[(((size_t)kc2 * 3 + 0) * Bb + bb) * 1024 + j];
            s1 += p3a[(((size_t)kc2 * 3 + 1) * Bb + bb) * 1024 + j];
            sx += p3a[(((size_t)kc2 * 3 + 2) * Bb + bb) * 1024 + j];
        }
        float r = 1.f / (1.f + expf(-(s0 + sb[((size_t)bb * OLEN + s) * 2048 + j])));
        float u = 1.f / (1.f + expf(-(s1 + sb[((size_t)bb * OLEN + s) * 2048 + 1024 + j])));
        float ht = tanhf(sx * r + sbx[((size_t)bb * OLEN + s) * 1024 + j]);
        float hp = h[(size_t)bb * 1024 + j];
        float h1 = u * hp + (1.f - u) * ht;
        float m = (s < ylens[bb] + 1) ? 1.f : 0.f;
        h1 = m * h1 + (1.f - m) * hp;
        xs[i] = h1;
        if (jb == 0) h1buf[(size_t)bb * 1024 + j] = h1;
    }
    __syncthreads();
    const int tx = tid & 63, ty = tid >> 6;
    const int j = jb * 64 + tx;
    const int b0 = ty * 8;
    float acc[8] = {};
    for (int kk = 0; kk < 64; kk++) {
        float w = Wdec[(size_t)(k0 + kk) * 512 + j];
#pragma unroll
        for (int i = 0; i < 8; i++) acc[i] += xs[(b0 + i) * 64 + kk] * w;
    }
#pragma unroll
    for (int i = 0; i < 8; i++) pd[((size_t)kc * Bb + b0 + i) * 512 + j] = acc[i];
}

// K3: en[b,t] = enc_att[b,t,:] . tanh(sum_kc pd); also zeroes cbuf
__global__ void k_en(const float* __restrict__ pd, const float* __restrict__ enc,
                     float* __restrict__ en, float* __restrict__ cbuf) {
    __shared__ float dqs[Aa];
    const int tid = threadIdx.x;
    const int b = blockIdx.y, tt = blockIdx.x;
    if (tid < 128) cbuf[(size_t)b * 1024 + tt * 128 + tid] = 0.f;
    for (int jj = tid; jj < Aa; jj += 256) {
        float sum = 0;
#pragma unroll
        for (int kc = 0; kc < 16; kc++) sum += pd[((size_t)kc * Bb + b) * Aa + jj];
        dqs[jj] = tanhf(sum);
    }
    __syncthreads();
    const int tx = tid & 63, ty = tid >> 6;
    for (int t2 = 0; t2 < 64; t2 += 4) {
        int t = tt * 64 + t2 + ty;
        if (t < Tt) {  // wave-uniform
            float acc = 0;
            const float* er = enc + ((size_t)b * Tt + t) * Aa;
#pragma unroll
            for (int i = 0; i < 8; i++) acc += er[tx + 64 * i] * dqs[tx + 64 * i];
#pragma unroll
            for (int off = 32; off > 0; off >>= 1) acc += __shfl_down(acc, off, 64);
            if (tx == 0) en[(size_t)b * 512 + t] = acc;
        }
    }
}

// K4: softmax over t + c = w_att @ hs_pad, atomics into cbuf.
// grid (2 e-tiles of 512, 4 t-chunks of 125, B), 128 threads.
__global__ void k_softc(const float* __restrict__ en, const float* __restrict__ hs,
                        const int* __restrict__ hlens, float* __restrict__ cbuf) {
    __shared__ float wts[Tt];
    __shared__ float red[128];
    const int tid = threadIdx.x;
    const int b = blockIdx.z;
    const int hlen = hlens[b];
    float mx = -1e30f;
    for (int t = tid; t < hlen; t += 128) mx = fmaxf(mx, en[(size_t)b * 512 + t]);
    red[tid] = mx;
    __syncthreads();
    for (int w = 64; w > 0; w >>= 1) {
        if (tid < w) red[tid] = fmaxf(red[tid], red[tid + w]);
        __syncthreads();
    }
    mx = red[0];
    __syncthreads();
    float ps = 0;
    for (int t = tid; t < Tt; t += 128) {
        float w = 0.f;
        if (t < hlen) w = expf(en[(size_t)b * 512 + t] - mx);
        wts[t] = w;
        ps += w;
    }
    red[tid] = ps;
    __syncthreads();
    for (int w = 64; w > 0; w >>= 1) {
        if (tid < w) red[tid] += red[tid + w];
        __syncthreads();
    }
    float inv = 1.f / red[0];
    __syncthreads();
    for (int t = tid; t < Tt; t += 128) wts[t] *= inv;
    __syncthreads();

    const int e0 = blockIdx.x * 512 + tid * 4;
    const int tc = blockIdx.y;
    int tstart = tc * 125;
    int tend = tstart + 125;
    if (tend > hlen) tend = hlen;
    float4 a0 = make_float4(0, 0, 0, 0), a1 = make_float4(0, 0, 0, 0);
    float4 a2 = make_float4(0, 0, 0, 0), a3 = make_float4(0, 0, 0, 0);
    int t = tstart;
    for (; t + 3 < tend; t += 4) {
        float w0 = wts[t], w1 = wts[t + 1], w2 = wts[t + 2], w3 = wts[t + 3];
        float4 h0 = *(const float4*)(&hs[((size_t)b * Tt + t) * Ee + e0]);
        float4 h1 = *(const float4*)(&hs[((size_t)b * Tt + t + 1) * Ee + e0]);
        float4 h2 = *(const float4*)(&hs[((size_t)b * Tt + t + 2) * Ee + e0]);
        float4 h3 = *(const float4*)(&hs[((size_t)b * Tt + t + 3) * Ee + e0]);
        a0.x += w0 * h0.x; a0.y += w0 * h0.y; a0.z += w0 * h0.z; a0.w += w0 * h0.w;
        a1.x += w1 * h1.x; a1.y += w1 * h1.y; a1.z += w1 * h1.z; a1.w += w1 * h1.w;
        a2.x += w2 * h2.x; a2.y += w2 * h2.y; a2.z += w2 * h2.z; a2.w += w2 * h2.w;
        a3.x += w3 * h3.x; a3.y += w3 * h3.y; a3.z += w3 * h3.z; a3.w += w3 * h3.w;
    }
    for (; t < tend; t++) {
        float w = wts[t];
        float4 hv = *(const float4*)(&hs[((size_t)b * Tt + t) * Ee + e0]);
        a0.x += w * hv.x; a0.y += w * hv.y; a0.z += w * hv.z; a0.w += w * hv.w;
    }
    a0.x += a1.x + a2.x + a3.x;
    a0.y += a1.y + a2.y + a3.y;
    a0.z += a1.z + a2.z + a3.z;
    a0.w += a1.w + a2.w + a3.w;
    float* cdst = &cbuf[(size_t)b * 1024 + e0];
    atomicAdd(cdst + 0, a0.x);
    atomicAdd(cdst + 1, a0.y);
    atomicAdd(cdst + 2, a0.z);
    atomicAdd(cdst + 3, a0.w);
}

// K5: cell2 split-K GEMM over [h1|c] (segmented staging from h1buf/cbuf).
// jb==0 & kc>=8 blocks copy their c chunk into x23s right half.
__global__ __launch_bounds__(256) void k_cell2(
    const float* __restrict__ h1buf, const float* __restrict__ cbuf,
    const float* __restrict__ U2, const float* __restrict__ Wc,
    const float* __restrict__ Ux2, const float* __restrict__ Wcx,
    float* __restrict__ p3b, float* __restrict__ x23s) {
    __shared__ float xs[Bb * 128];
    const int tid = threadIdx.x;
    const int jb = blockIdx.x, kc = blockIdx.y;
    const int k0 = kc * 128;
    const bool seg0 = (kc < 8);
    for (int i = tid; i < Bb * 128; i += 256) {
        int bb = i >> 7, k = i & 127;
        float v = seg0 ? h1buf[(size_t)bb * 1024 + k0 + k]
                       : cbuf[(size_t)bb * 1024 + (k0 - 1024) + k];
        xs[i] = v;
        if (!seg0 && jb == 0) x23s[(size_t)bb * 2048 + 1024 + (k0 - 1024) + k] = v;
    }
    __syncthreads();
    const int tx = tid & 63, ty = tid >> 6;
    const int j = jb * 64 + tx;
    const int b0 = ty * 8;
    const float* Wg = seg0 ? U2 : Wc;
    const float* Wx = seg0 ? Ux2 : Wcx;
    const int kbase = seg0 ? k0 : (k0 - 1024);
    float ag[8] = {}, au[8] = {}, ax[8] = {};
    for (int kk = 0; kk < 128; kk++) {
        const float* wgr = Wg + (size_t)(kbase + kk) * 2048;
        const float* wxr = Wx + (size_t)(kbase + kk) * 1024;
        float wg0 = wgr[j], wg1 = wgr[j + 1024], wx0 = wxr[j];
#pragma unroll
        for (int i = 0; i < 8; i++) {
            float xv = xs[(b0 + i) * 128 + kk];
            ag[i] += xv * wg0;
            au[i] += xv * wg1;
            ax[i] += xv * wx0;
        }
    }
#pragma unroll
    for (int i = 0; i < 8; i++) {
        p3b[(((size_t)kc * 3 + 0) * Bb + b0 + i) * 1024 + j] = ag[i];
        p3b[(((size_t)kc * 3 + 1) * Bb + b0 + i) * 1024 + j] = au[i];
        p3b[(((size_t)kc * 3 + 2) * Bb + b0 + i) * 1024 + j] = ax[i];
    }
}

// finalize: comb2 for s=99 -> x23 left half of last step
__global__ void k_final(const float* __restrict__ p3b, const float* __restrict__ h1buf,
                        const float* __restrict__ b2, const float* __restrict__ bUx2,
                        const int* __restrict__ ylens, float* __restrict__ x23last) {
    int gid = blockIdx.x * 256 + threadIdx.x;
    int b = gid >> 10, j = gid & 1023;
    float s0 = 0, s1 = 0, xa = 0, xb = 0;
#pragma unroll
    for (int kc = 0; kc < 16; kc++) {
        s0 += p3b[(((size_t)kc * 3 + 0) * Bb + b) * 1024 + j];
        s1 += p3b[(((size_t)kc * 3 + 1) * Bb + b) * 1024 + j];
        float px = p3b[(((size_t)kc * 3 + 2) * Bb + b) * 1024 + j];
        if (kc < 8) xa += px; else xb += px;
    }
    float r = 1.f / (1.f + expf(-(s0 + b2[j])));
    float u = 1.f / (1.f + expf(-(s1 + b2[1024 + j])));
    float h2t = tanhf((xa + bUx2[j]) * r + xb);
    float h1v = h1buf[(size_t)b * 1024 + j];
    float h2 = u * h1v + (1.f - u) * h2t;
    float m = (99 < ylens[b] + 1) ? 1.f : 0.f;
    h2 = m * h2 + (1.f - m) * h1v;
    x23last[(size_t)b * 2048 + j] = h2;
}

// ---------------- batched final phase (128x128 tiles) ----------------

// mo[3200,512] = maxout( [h2|c](3200x2048) @ [Ws;We] + eys @ Wy + bs )
__global__ __launch_bounds__(256) void k_gemmL(const float* __restrict__ x23a,
                                               const float* __restrict__ eys,
                                               const float* __restrict__ Ws,
                                               const float* __restrict__ We,
                                               const float* __restrict__ Wy,
                                               const float* __restrict__ bs,
                                               float* __restrict__ mo) {
    __shared__ float As[16][132];
    __shared__ float Bs[16][132];
    const int tid = threadIdx.x;
    const int row0 = blockIdx.y * 128, col0 = blockIdx.x * 128;
    const int ty = tid >> 4, tx = tid & 15;
    float acc[8][8] = {};
    for (int kk = 0; kk < 2304; kk += 16) {
#pragma unroll
        for (int l = 0; l < 2; l++) {
            int idx = tid + l * 256;
            int r = row0 + (idx >> 2);
            int c4 = (idx & 3) * 4;
            float4 v;
            if (kk < 2048) {
                v = *(const float4*)(&x23a[(size_t)r * 2048 + kk + c4]);
            } else {
                int bI = r & 31, sI = r >> 5;
                v = *(const float4*)(&eys[((size_t)bI * OLEN + sI) * EMBc + (kk - 2048) + c4]);
            }
            int rl = idx >> 2;
            As[c4 + 0][rl] = v.x; As[c4 + 1][rl] = v.y; As[c4 + 2][rl] = v.z; As[c4 + 3][rl] = v.w;
        }
#pragma unroll
        for (int l = 0; l < 2; l++) {
            int idx = tid + l * 256;
            int r = idx >> 5, c4 = (idx & 31) * 4;
            int rowk = kk + r;
            const float* wr = (rowk < 1024) ? &Ws[(size_t)rowk * 1024]
                             : (rowk < 2048) ? &We[(size_t)(rowk - 1024) * 1024]
                                             : &Wy[(size_t)(rowk - 2048) * 1024];
            float4 v = *(const float4*)(&wr[col0 + c4]);
            Bs[r][c4 + 0] = v.x; Bs[r][c4 + 1] = v.y; Bs[r][c4 + 2] = v.z; Bs[r][c4 + 3] = v.w;
        }
        __syncthreads();
#pragma unroll
        for (int k = 0; k < 16; k++) {
            float a[8], b[8];
#pragma unroll
            for (int i = 0; i < 8; i++) a[i] = As[k][ty * 8 + i];
#pragma unroll
            for (int j = 0; j < 8; j++) b[j] = Bs[k][tx * 8 + j];
#pragma unroll
            for (int i = 0; i < 8; i++)
#pragma unroll
                for (int j = 0; j < 8; j++) acc[i][j] += a[i] * b[j];
        }
        __syncthreads();
    }
#pragma unroll
    for (int i = 0; i < 8; i++) {
        int r = row0 + ty * 8 + i;
#pragma unroll
        for (int j = 0; j < 8; j += 2) {
            int c = col0 + tx * 8 + j;
            float v0 = acc[i][j + 0] + bs[c + 0];
            float v1 = acc[i][j + 1] + bs[c + 1];
            mo[(size_t)r * 512 + (c >> 1)] = fmaxf(v0, v1);
        }
    }
}

// z = mo(3200x512) @ Wlogit(512x5000) + blogit -> out rows (b,s)
__global__ __launch_bounds__(256) void k_gemmZ(const float* __restrict__ mo,
                                               const float* __restrict__ Wl,
                                               const float* __restrict__ bl,
                                               float* __restrict__ out) {
    __shared__ float As[16][132];
    __shared__ float Bs[16][132];
    const int tid = threadIdx.x;
    const int row0 = blockIdx.y * 128, col0 = blockIdx.x * 128;
    const int ty = tid >> 4, tx = tid & 15;
    float acc[8][8] = {};
    for (int kk = 0; kk < 512; kk += 16) {
#pragma unroll
        for (int l = 0; l < 2; l++) {
            int idx = tid + l * 256;
            int rl = idx >> 2, c4 = (idx & 3) * 4;
            float4 v = *(const float4*)(&mo[(size_t)(row0 + rl) * 512 + kk + c4]);
            As[c4 + 0][rl] = v.x; As[c4 + 1][rl] = v.y; As[c4 + 2][rl] = v.z; As[c4 + 3][rl] = v.w;
        }
#pragma unroll
        for (int l = 0; l < 2; l++) {
            int idx = tid + l * 256;
            int r = idx >> 5, c4 = (idx & 31) * 4;
            int cb = col0 + c4;
            if (cb + 3 < Oo) {
                float4 v = *(const float4*)(&Wl[(size_t)(kk + r) * Oo + cb]);
                Bs[r][c4 + 0] = v.x; Bs[r][c4 + 1] = v.y; Bs[r][c4 + 2] = v.z; Bs[r][c4 + 3] = v.w;
            } else {
#pragma unroll
                for (int q = 0; q < 4; q++) {
                    int c = cb + q; if (c > Oo - 1) c = Oo - 1;
                    Bs[r][c4 + q] = Wl[(size_t)(kk + r) * Oo + c];
                }
            }
        }
        __syncthreads();
#pragma unroll
        for (int k = 0; k < 16; k++) {
            float a[8], b[8];
#pragma unroll
            for (int i = 0; i < 8; i++) a[i] = As[k][ty * 8 + i];
#pragma unroll
            for (int j = 0; j < 8; j++) b[j] = Bs[k][tx * 8 + j];
#pragma unroll
            for (int i = 0; i < 8; i++)
#pragma unroll
                for (int j = 0; j < 8; j++) acc[i][j] += a[i] * b[j];
        }
        __syncthreads();
    }
#pragma unroll
    for (int i = 0; i < 8; i++) {
        int r = row0 + ty * 8 + i;
        int bI = r & 31, sI = r >> 5;
        float* zr = out + ((size_t)bI * OLEN + sI) * Oo;
#pragma unroll
        for (int j = 0; j < 8; j++) {
            int c = col0 + tx * 8 + j;
            if (c < Oo) zr[c] = acc[i][j] + bl[c];
        }
    }
}

// in-place row softmax over d_out rows; block r -> (b = r&31, s = r>>5)
__global__ void k_osm(float* __restrict__ out) {
    __shared__ float red[256];
    __shared__ float ev[Oo];
    const int tid = threadIdx.x;
    const int r = blockIdx.x;
    const int bI = r & 31, sI = r >> 5;
    float* zr = out + ((size_t)bI * OLEN + sI) * Oo;
    float mx = -1e30f;
    for (int i = tid; i < Oo; i += 256) mx = fmaxf(mx, zr[i]);
    red[tid] = mx;
    __syncthreads();
    for (int w = 128; w > 0; w >>= 1) {
        if (tid < w) red[tid] = fmaxf(red[tid], red[tid + w]);
        __syncthreads();
    }
    mx = red[0];
    __syncthreads();
    float ps = 0;
    for (int i = tid; i < Oo; i += 256) {
        float e = expf(zr[i] - mx);
        ev[i] = e;
        ps += e;
    }
    red[tid] = ps;
    __syncthreads();
    for (int w = 128; w > 0; w >>= 1) {
        if (tid < w) red[tid] += red[tid + w];
        __syncthreads();
    }
    float inv = 1.f / red[0];
    for (int i = tid; i < Oo; i += 256) zr[i] = ev[i] * inv;
}

// ---------------- launch ----------------

extern "C" void kernel_launch(void* const* d_in, const int* in_sizes, int n_in,
                              void* d_out, int out_size, void* d_ws, size_t ws_size,
                              hipStream_t stream) {
    const float* hs    = (const float*)d_in[0];
    const int*   hlens = (const int*)d_in[1];
    const int*   ys    = (const int*)d_in[2];
    const float* embed = (const float*)d_in[3];
    const float* W1_W  = (const float*)d_in[4];
    const float* b1_W  = (const float*)d_in[5];
    const float* W1_Wx = (const float*)d_in[6];
    const float* b1_Wx = (const float*)d_in[7];
    const float* U1    = (const float*)d_in[8];
    const float* Ux1   = (const float*)d_in[9];
    const float* U2    = (const float*)d_in[10];
    const float* b2    = (const float*)d_in[11];
    const float* Wc    = (const float*)d_in[12];
    const float* Ux2   = (const float*)d_in[13];
    const float* bUx2  = (const float*)d_in[14];
    const float* Wcx   = (const float*)d_in[15];
    const float* Winit = (const float*)d_in[16];
    const float* binit = (const float*)d_in[17];
    const float* Ws    = (const float*)d_in[18];
    const float* bs    = (const float*)d_in[19];
    const float* Wy    = (const float*)d_in[20];
    const float* We    = (const float*)d_in[21];
    const float* Wlog  = (const float*)d_in[22];
    const float* blog  = (const float*)d_in[23];
    const float* Wenc  = (const float*)d_in[24];
    const float* Wdec  = (const float*)d_in[25];
    float* out = (float*)d_out;
    float* wsp = (float*)d_ws;

    // ws layout (floats) -- total ~22.4M floats ~= 89.5 MB
    float* enc_att = wsp;                                    // 32*500*512   = 8,192,000
    float* sb      = enc_att + (size_t)Bb * Tt * Aa;         // 32*100*2048  = 6,553,600
    float* sbx     = sb      + (size_t)Bb * OLEN * 2048;     // 32*100*1024  = 3,276,800
    float* eys     = sbx     + (size_t)Bb * OLEN * 1024;     // 32*100*256   =   819,200
    float* h       = eys     + (size_t)Bb * OLEN * EMBc;     // 32*1024
    float* h1buf   = h       + (size_t)Bb * 1024;            // 32*1024
    float* cbuf    = h1buf   + (size_t)Bb * 1024;            // 32*1024
    float* en      = cbuf    + (size_t)Bb * 1024;            // 32*512
    float* pd      = en      + (size_t)Bb * 512;             // 16*32*512    =   262,144
    float* p3a     = pd      + (size_t)16 * Bb * 512;        // 16*3*32*1024 = 1,572,864
    float* p3b     = p3a     + (size_t)16 * 3 * Bb * 1024;   // 16*3*32*1024 = 1,572,864
    int*   ylens   = (int*)(p3b + (size_t)16 * 3 * Bb * 1024);
    float* hm      = pd;    // alias: precompute only
    float* mo      = p3a;   // alias: final phase only (1.64M <= 3.15M of p3a+p3b)
    // [h2|c] per step hosted in d_out (dead until final phase): 3200 x 2048 row-major
    float* xall    = out;

    // ---- precompute ----
    k_ylens<<<1, 64, 0, stream>>>(ys, ylens);
    k_embed<<<Bb * OLEN, EMBc, 0, stream>>>(ys, embed, eys);
    k_hmean<<<dim3(4, Bb), 256, 0, stream>>>(hs, hlens, hm);
    k_gemm128<0><<<dim3(8, 1), 256, 0, stream>>>(hm, Winit, binit, h, Bb, 1024, 1024);
    k_gemm128<0><<<dim3(16, 25), 256, 0, stream>>>(eys, W1_W, b1_W, sb, Bb * OLEN, EMBc, 2048);
    k_gemm128<0><<<dim3(8, 25), 256, 0, stream>>>(eys, W1_Wx, b1_Wx, sbx, Bb * OLEN, EMBc, 1024);
    k_gemm128<1><<<dim3(4, 125), 256, 0, stream>>>(hs, Wenc, nullptr, enc_att, Bb * Tt, Ee, Aa);

    // ---- recurrence: 5 launches/step ----
    for (int s = 0; s < OLEN; s++) {
        float* x23s = xall + (size_t)s * Bb * 2048;
        float* x23prev = (s == 0) ? xall : (xall + (size_t)(s - 1) * Bb * 2048);
        k_cell1<<<dim3(16, 16), 256, 0, stream>>>(h, (s == 0) ? 1 : 0, p3b, h1buf,
                                                  b2, bUx2, ylens, s - 1, U1, Ux1,
                                                  p3a, h, x23prev);
        k_dq<<<dim3(8, 16), 256, 0, stream>>>(p3a, sb, sbx, h, ylens, s, Wdec, pd, h1buf);
        k_en<<<dim3(8, Bb), 256, 0, stream>>>(pd, enc_att, en, cbuf);
        k_softc<<<dim3(2, 4, Bb), 128, 0, stream>>>(en, hs, hlens, cbuf);
        k_cell2<<<dim3(16, 16), 256, 0, stream>>>(h1buf, cbuf, U2, Wc, Ux2, Wcx, p3b, x23s);
    }
    // finalize h2 for s=99 into x23
    k_final<<<128, 256, 0, stream>>>(p3b, h1buf, b2, bUx2, ylens,
                                     xall + (size_t)99 * Bb * 2048);

    // ---- batched logit path over all (b, s) ----
    k_gemmL<<<dim3(8, 25), 256, 0, stream>>>(xall, eys, Ws, We, Wy, bs, mo);
    k_gemmZ<<<dim3(40, 25), 256, 0, stream>>>(mo, Wlog, blog, out);
    k_osm<<<Bb * OLEN, 256, 0, stream>>>(out);
}